// Round 1
// baseline (161.594 us; speedup 1.0000x reference)
//
#include <hip/hip_runtime.h>

#define U_N 100000
#define I_N 100000
#define D_N 64
#define B_N 16384
#define T_N 1638400
#define R_N 5
#define NSEG (B_N * R_N)
#define CHUNK 16

// Kernel A: per-item full-row sum of Mr. One wave (64 lanes) per row, lane=dim.
__global__ void rowsum_kernel(const float* __restrict__ Mr, float* __restrict__ rowsum) {
    int wave = (blockIdx.x * blockDim.x + threadIdx.x) >> 6;
    int lane = threadIdx.x & 63;
    if (wave >= I_N) return;
    float v = Mr[(long)wave * D_N + lane];
    #pragma unroll
    for (int off = 32; off >= 1; off >>= 1) v += __shfl_xor(v, off, 64);
    if (lane == 0) rowsum[wave] = v;
}

// Kernel B: segmented sum over sorted seg_ids. Each thread owns CHUNK contiguous
// elements, accumulates locally while the segment id is unchanged (sorted input
// => few changes), flushes with one atomicAdd pair per distinct segment touched.
__global__ void seg_kernel(const int* __restrict__ flat_items,
                           const int* __restrict__ seg_ids,
                           const int* __restrict__ item_idx,
                           const float* __restrict__ rowsum,
                           float* __restrict__ seg_sum,
                           int* __restrict__ seg_cnt) {
    int tid = blockIdx.x * blockDim.x + threadIdx.x;
    long base = (long)tid * CHUNK;
    if (base >= T_N) return;

    const int4* fi4 = (const int4*)(flat_items + base);
    const int4* si4 = (const int4*)(seg_ids + base);

    int cur_seg = -1;
    float acc = 0.f;
    int cnt = 0;

    #pragma unroll
    for (int c = 0; c < CHUNK / 4; ++c) {
        int4 fi = fi4[c];
        int4 si = si4[c];
        int f[4] = {fi.x, fi.y, fi.z, fi.w};
        int s[4] = {si.x, si.y, si.z, si.w};
        #pragma unroll
        for (int j = 0; j < 4; ++j) {
            int sg = s[j];
            if (sg != cur_seg) {
                if (cnt > 0) {
                    atomicAdd(&seg_sum[cur_seg], acc);
                    atomicAdd(&seg_cnt[cur_seg], cnt);
                }
                cur_seg = sg; acc = 0.f; cnt = 0;
            }
            int it = f[j];
            // match = flat_items[t] == item_idx[seg_ids[t] / R]
            if (it != item_idx[sg / R_N]) {
                acc += rowsum[it];
                cnt += 1;
            }
        }
    }
    if (cnt > 0) {
        atomicAdd(&seg_sum[cur_seg], acc);
        atomicAdd(&seg_cnt[cur_seg], cnt);
    }
}

// Kernel C: one wave per sample. lane=dim loads emb rows coalesced (256B/row),
// shuffle-reduces dot(ue,ie) and sum(ie); lane 0 folds in the 5 segment terms.
__global__ void final_kernel(const int* __restrict__ user_idx,
                             const int* __restrict__ item_idx,
                             const float* __restrict__ user_emb,
                             const float* __restrict__ item_emb,
                             const float* __restrict__ user_bias,
                             const float* __restrict__ item_bias,
                             const float* __restrict__ global_avg,
                             const float* __restrict__ seg_sum,
                             const int* __restrict__ seg_cnt,
                             float* __restrict__ out) {
    int wave = (blockIdx.x * blockDim.x + threadIdx.x) >> 6;
    int lane = threadIdx.x & 63;
    if (wave >= B_N) return;
    int u = user_idx[wave];
    int it = item_idx[wave];
    float ue = user_emb[(long)u * D_N + lane];
    float ie = item_emb[(long)it * D_N + lane];
    float dot = ue * ie;
    float isum = ie;
    #pragma unroll
    for (int off = 32; off >= 1; off >>= 1) {
        dot += __shfl_xor(dot, off, 64);
        isum += __shfl_xor(isum, off, 64);
    }
    if (lane == 0) {
        float uu = 0.f;
        #pragma unroll
        for (int r = 0; r < R_N; ++r) {
            int s = wave * R_N + r;
            int c = seg_cnt[s];
            if (c > 0) uu += seg_sum[s] / sqrtf((float)c);
        }
        float rui = dot + uu * isum + user_bias[u] + item_bias[it] + global_avg[0];
        rui = fminf(fmaxf(rui, 1.0f), 5.0f);
        out[wave] = rui;
    }
}

extern "C" void kernel_launch(void* const* d_in, const int* in_sizes, int n_in,
                              void* d_out, int out_size, void* d_ws, size_t ws_size,
                              hipStream_t stream) {
    const int*   user_idx   = (const int*)d_in[0];
    const int*   item_idx   = (const int*)d_in[1];
    const int*   flat_items = (const int*)d_in[2];
    const int*   seg_ids    = (const int*)d_in[3];
    const float* user_emb   = (const float*)d_in[4];
    const float* item_emb   = (const float*)d_in[5];
    const float* Mr         = (const float*)d_in[6];
    const float* user_bias  = (const float*)d_in[7];
    const float* item_bias  = (const float*)d_in[8];
    const float* global_avg = (const float*)d_in[9];
    float* out = (float*)d_out;

    // workspace layout: [rowsum: I_N floats][seg_sum: NSEG floats][seg_cnt: NSEG ints]
    float* rowsum  = (float*)d_ws;
    float* seg_sum = rowsum + I_N;
    int*   seg_cnt = (int*)(seg_sum + NSEG);

    // zero seg_sum + seg_cnt (contiguous) — ws is poisoned 0xAA before each call
    hipMemsetAsync(seg_sum, 0, (size_t)NSEG * sizeof(float) * 2, stream);

    rowsum_kernel<<<(I_N * 64 + 255) / 256, 256, 0, stream>>>(Mr, rowsum);
    seg_kernel<<<(T_N / CHUNK + 255) / 256, 256, 0, stream>>>(
        flat_items, seg_ids, item_idx, rowsum, seg_sum, seg_cnt);
    final_kernel<<<(B_N * 64 + 255) / 256, 256, 0, stream>>>(
        user_idx, item_idx, user_emb, item_emb, user_bias, item_bias,
        global_avg, seg_sum, seg_cnt, out);
}